// Round 6
// baseline (183.689 us; speedup 1.0000x reference)
//
#include <hip/hip_runtime.h>
#include <hip/hip_bf16.h>

// Fused: qp=QWq^T+bq etc, then O = Qp (Kp^T Vp) (no softmax -> associativity),
// out[b,c,h,w] = O[w][c] + q[b,c,h,w].  bf16 MFMA, fp32 accum.
// Round 6: R2's exact resource shape (78KB LDS, 2 blocks/CU, one-shot grid,
// natural order) + 2 tiles per block (grid 2048, bh=2*bid+t) so tile-1 loads
// overlap tile-0 compute. Live tile window stays ~1024 ids (<LLC), unlike
// R3's 8-tile stride that thrashed the LLC. Staging-only XOR swizzle.

typedef __bf16 bf16x8 __attribute__((ext_vector_type(8)));
typedef float  f32x4  __attribute__((ext_vector_type(4)));

#define LDP 68    // pixel-major row stride (bf16 elems): 136B rows, 8B-aligned
#define LDX 132   // channel-major row stride: 264B rows, 8B-aligned

// LDS region offsets (in ushort units)
#define OF_A 0        // sK[128][68]  -> later sTt[64][68]
#define OF_B 8704     // sV[128][68]  -> later sQ[128][68]
#define OF_C 17408    // sKPt[64][132]-> later sQP[128][68] (spills 256 into D)
#define OF_D 25856    // sVPt[64][132]
#define OF_W 34304    // sWq[64][68]
#define OF_SB 38656   // float sB[192]: [0:64)=bq [64:128)=bk [128:192)=bv
#define LDS_USHORTS (38656 + 384)

// XOR swizzle (16B granule, key = row bits 2..4) for staged-input buffers only
#define SWZ(row, col) ((col) ^ ((((row) >> 2) & 7) << 3))

__device__ __forceinline__ unsigned short f2bf(float x) {
  __hip_bfloat16 h = __float2bfloat16(x);           // RNE
  return __builtin_bit_cast(unsigned short, h);
}
__device__ __forceinline__ float bf2f(unsigned short u) {
  unsigned int t = ((unsigned int)u) << 16;
  return __builtin_bit_cast(float, t);
}
__device__ __forceinline__ unsigned int pack2(float a, float b) {
  return (unsigned int)f2bf(a) | ((unsigned int)f2bf(b) << 16);
}
__device__ __forceinline__ bf16x8 cvt8(float4 a, float4 b) {
  union { unsigned int u[4]; bf16x8 v; } r;
  r.u[0] = pack2(a.x, a.y); r.u[1] = pack2(a.z, a.w);
  r.u[2] = pack2(b.x, b.y); r.u[3] = pack2(b.z, b.w);
  return r.v;
}
// load 8 contiguous bf16 (8B-aligned) as an MFMA fragment
__device__ __forceinline__ bf16x8 ld8(const unsigned short* p) {
  uint2 lo = *reinterpret_cast<const uint2*>(p);
  uint2 hi = *reinterpret_cast<const uint2*>(p + 4);
  uint4 t;
  t.x = lo.x; t.y = lo.y; t.z = hi.x; t.w = hi.y;
  return __builtin_bit_cast(bf16x8, t);
}

__global__ __launch_bounds__(512, 4)
void fused_mha(const float* __restrict__ q, const float* __restrict__ k,
               const float* __restrict__ v,
               const float* __restrict__ wq, const float* __restrict__ bq,
               const float* __restrict__ wk, const float* __restrict__ bk,
               const float* __restrict__ wv, const float* __restrict__ bv,
               float* __restrict__ out)
{
  __shared__ __align__(16) unsigned short lds[LDS_USHORTS];
  unsigned short* sK   = lds + OF_A;   // [128][LDP] pixel-major bf16 (SWZ)
  unsigned short* sV   = lds + OF_B;   // (SWZ)
  unsigned short* sKPt = lds + OF_C;   // [64][LDX] channel-major (plain)
  unsigned short* sVPt = lds + OF_D;   // (plain)
  unsigned short* sWq  = lds + OF_W;   // [64][LDP] natural [o][c] (plain)
  unsigned short* sTt  = lds + OF_A;   // [64][LDP]  (aliases dead sK, plain)
  unsigned short* sQ   = lds + OF_B;   // [128][LDP] (aliases dead sV, SWZ)
  unsigned short* sQP  = lds + OF_C;   // [128][LDP] (aliases dead sKPt+, plain)
  float* sB = (float*)(lds + OF_SB);

  const int tid  = threadIdx.x;
  const int lane = tid & 63;
  const int ww   = tid >> 6;     // wave 0..7
  const int l15  = lane & 15;
  const int g    = lane >> 4;    // 0..3

  const size_t CS = 128*128;

  // staging thread mapping: 4 consecutive w rows, 2 channels, 2 units
  const int sw0   = 4*(tid & 31);
  const int scA   = 2*((tid >> 5) & 15);
  const int swsel = ((tid & 31) & 7) << 3;   // ((row>>2)&7)<<3 for rows sw0..+3

  // ---------------- prologue: W frags, Wq, biases, tile-0 prefetch --------
  const int rt = ww & 3;
  const int cb = (ww >> 2) * 4;
  bf16x8 wkf[2], wvf[2];
  #pragma unroll
  for (int ks = 0; ks < 2; ++ks) {
    const float* pk = wk + (16*rt + l15)*64 + 8*g + 32*ks;
    const float* pv = wv + (16*rt + l15)*64 + 8*g + 32*ks;
    wkf[ks] = cvt8(*(const float4*)pk, *(const float4*)(pk+4));
    wvf[ks] = cvt8(*(const float4*)pv, *(const float4*)(pv+4));
  }
  {
    const int o  = tid >> 3;
    const int c0 = (tid & 7) * 8;
    float4 a = *(const float4*)(wq + o*64 + c0);
    float4 b = *(const float4*)(wq + o*64 + c0 + 4);
    unsigned short* p = &sWq[o*LDP + c0];
    ((uint2*)p)[0] = make_uint2(pack2(a.x,a.y), pack2(a.z,a.w));
    ((uint2*)p)[1] = make_uint2(pack2(b.x,b.y), pack2(b.z,b.w));
  }
  if (tid < 64)        sB[tid] = bq[tid];
  else if (tid < 128)  sB[tid] = bk[tid-64];
  else if (tid < 192)  sB[tid] = bv[tid-128];

  // tile-0 loads into registers (bh = 2*blockIdx.x)
  float4 qreg[4], kreg[4], vreg[4];
  {
    const int bh = blockIdx.x << 1;
    const size_t b0 = (size_t)(bh >> 7)*(64*CS) + (size_t)(bh & 127)*128;
    #pragma unroll
    for (int u = 0; u < 2; ++u) {
      int c = scA + 32*u;
      const float* pq = q + b0 + (size_t)c*CS + sw0;
      const float* pk = k + b0 + (size_t)c*CS + sw0;
      const float* pv = v + b0 + (size_t)c*CS + sw0;
      qreg[2*u+0] = *(const float4*)pq;  qreg[2*u+1] = *(const float4*)(pq + CS);
      kreg[2*u+0] = *(const float4*)pk;  kreg[2*u+1] = *(const float4*)(pk + CS);
      vreg[2*u+0] = *(const float4*)pv;  vreg[2*u+1] = *(const float4*)(pv + CS);
    }
  }

  #pragma unroll
  for (int t = 0; t < 2; ++t) {
    const int bh = (blockIdx.x << 1) + t;
    const size_t base = (size_t)(bh >> 7)*(64*CS) + (size_t)(bh & 127)*128;
    const size_t nbase = base + 128;   // bh+1 (same batch unless bh&127==127;
                                       // bh is even here so bh+1 never wraps)

    // ---------- PW: drain kreg/vreg -> sK/sV (swizzled); issue k/v(t+1) ----
    #pragma unroll
    for (int u = 0; u < 2; ++u) {
      int c = (scA + 32*u) ^ swsel;
      const float* ka = (const float*)&kreg[2*u];
      const float* kb = (const float*)&kreg[2*u+1];
      const float* va = (const float*)&vreg[2*u];
      const float* vb = (const float*)&vreg[2*u+1];
      #pragma unroll
      for (int j = 0; j < 4; ++j) {
        *(unsigned int*)&sK[(sw0+j)*LDP + c] = pack2(ka[j], kb[j]);
        *(unsigned int*)&sV[(sw0+j)*LDP + c] = pack2(va[j], vb[j]);
      }
    }
    if (t == 0) {   // registers just died; issue next-tile k/v loads NOW
      #pragma unroll
      for (int u = 0; u < 2; ++u) {
        int c = scA + 32*u;
        const float* pk = k + nbase + (size_t)c*CS + sw0;
        const float* pv = v + nbase + (size_t)c*CS + sw0;
        kreg[2*u+0] = *(const float4*)pk;  kreg[2*u+1] = *(const float4*)(pk + CS);
        vreg[2*u+0] = *(const float4*)pv;  vreg[2*u+1] = *(const float4*)(pv + CS);
      }
    }
    __syncthreads();

    // ---------- P1: Kp^T[o][x], Vp^T[o][x] ----------
    {
      f32x4 z = {0.f,0.f,0.f,0.f};
      f32x4 acck[4] = {z,z,z,z}, accv[4] = {z,z,z,z};
      #pragma unroll
      for (int ks = 0; ks < 2; ++ks) {
        #pragma unroll
        for (int cc = 0; cc < 4; ++cc) {
          int row = 16*(cb+cc) + l15;
          int col = SWZ(row, 32*ks + 8*g);
          bf16x8 bk8 = ld8(&sK[row*LDP + col]);
          bf16x8 bv8 = ld8(&sV[row*LDP + col]);
          acck[cc] = __builtin_amdgcn_mfma_f32_16x16x32_bf16(wkf[ks], bk8, acck[cc], 0, 0, 0);
          accv[cc] = __builtin_amdgcn_mfma_f32_16x16x32_bf16(wvf[ks], bv8, accv[cc], 0, 0, 0);
        }
      }
      #pragma unroll
      for (int cc = 0; cc < 4; ++cc) {
        int x = 16*(cb+cc) + l15;
        #pragma unroll
        for (int r = 0; r < 4; ++r) {
          int o = 16*rt + 4*g + r;
          sKPt[o*LDX + x] = f2bf(acck[cc][r] + sB[64 + o]);
          sVPt[o*LDX + x] = f2bf(accv[cc][r] + sB[128 + o]);
        }
      }
    }
    __syncthreads();

    // ---------- P2: Tt = (Kp^T Vp)^T; drain q -> sQ; issue q(t+1) ----------
    {
      const int rt2 = ww >> 1;
      const int cb2 = (ww & 1) * 2;
      f32x4 z = {0.f,0.f,0.f,0.f};
      f32x4 acc[2] = {z,z};
      #pragma unroll
      for (int ks = 0; ks < 4; ++ks) {
        bf16x8 a = ld8(&sVPt[(16*rt2 + l15)*LDX + 32*ks + 8*g]);
        #pragma unroll
        for (int cc = 0; cc < 2; ++cc) {
          bf16x8 b = ld8(&sKPt[(16*(cb2+cc) + l15)*LDX + 32*ks + 8*g]);
          acc[cc] = __builtin_amdgcn_mfma_f32_16x16x32_bf16(a, b, acc[cc], 0, 0, 0);
        }
      }
      // drain q regs -> sQ (sV region dead after P1)
      #pragma unroll
      for (int u = 0; u < 2; ++u) {
        int c = (scA + 32*u) ^ swsel;
        const float* qa = (const float*)&qreg[2*u];
        const float* qb = (const float*)&qreg[2*u+1];
        #pragma unroll
        for (int j = 0; j < 4; ++j)
          *(unsigned int*)&sQ[(sw0+j)*LDP + c] = pack2(qa[j], qb[j]);
      }
      if (t == 0) {   // q regs just died; issue next-tile q loads
        #pragma unroll
        for (int u = 0; u < 2; ++u) {
          int c = scA + 32*u;
          const float* pq = q + nbase + (size_t)c*CS + sw0;
          qreg[2*u+0] = *(const float4*)pq;  qreg[2*u+1] = *(const float4*)(pq + CS);
        }
      }
      #pragma unroll
      for (int cc = 0; cc < 2; ++cc) {
        int d = 16*(cb2+cc) + l15;
        #pragma unroll
        for (int r = 0; r < 4; ++r)
          sTt[(16*rt2 + 4*g + r)*LDP + d] = f2bf(acc[cc][r]);
      }
    }
    __syncthreads();

    // ---------- P3: Qp[w][o] -> sQP ----------
    {
      f32x4 z = {0.f,0.f,0.f,0.f};
      f32x4 acc[4] = {z,z,z,z};
      #pragma unroll
      for (int ks = 0; ks < 2; ++ks) {
        int arow = 16*ww + l15;
        bf16x8 a = ld8(&sQ[arow*LDP + SWZ(arow, 32*ks + 8*g)]);
        #pragma unroll
        for (int ct = 0; ct < 4; ++ct) {
          bf16x8 b = ld8(&sWq[(16*ct + l15)*LDP + 32*ks + 8*g]);
          acc[ct] = __builtin_amdgcn_mfma_f32_16x16x32_bf16(a, b, acc[ct], 0, 0, 0);
        }
      }
      #pragma unroll
      for (int ct = 0; ct < 4; ++ct) {
        float bias = sB[16*ct + l15];
        #pragma unroll
        for (int r = 0; r < 4; ++r)
          sQP[(16*ww + 4*g + r)*LDP + 16*ct + l15] = f2bf(acc[ct][r] + bias);
      }
    }
    // no barrier: sQP rows [16*ww,16*ww+16) produced and consumed by SAME wave

    // ---------- P4: O[w][c] = Qp·Tt^T; out = O^T + q ----------
    {
      f32x4 z = {0.f,0.f,0.f,0.f};
      f32x4 acc[4] = {z,z,z,z};
      #pragma unroll
      for (int ks = 0; ks < 2; ++ks) {
        bf16x8 a = ld8(&sQP[(16*ww + l15)*LDP + 32*ks + 8*g]);
        #pragma unroll
        for (int ct = 0; ct < 4; ++ct) {
          bf16x8 b = ld8(&sTt[(16*ct + l15)*LDP + 32*ks + 8*g]);
          acc[ct] = __builtin_amdgcn_mfma_f32_16x16x32_bf16(a, b, acc[ct], 0, 0, 0);
        }
      }
      #pragma unroll
      for (int ct = 0; ct < 4; ++ct) {
        int c  = 16*ct + l15;
        int w0 = 16*ww + 4*g;
        float4 o4;
        o4.x = acc[ct][0] + bf2f(sQ[(w0+0)*LDP + SWZ(w0+0, c)]);
        o4.y = acc[ct][1] + bf2f(sQ[(w0+1)*LDP + SWZ(w0+1, c)]);
        o4.z = acc[ct][2] + bf2f(sQ[(w0+2)*LDP + SWZ(w0+2, c)]);
        o4.w = acc[ct][3] + bf2f(sQ[(w0+3)*LDP + SWZ(w0+3, c)]);
        *reinterpret_cast<float4*>(out + base + (size_t)c * CS + w0) = o4;
      }
    }
    if (t == 0) __syncthreads();   // protect LDS before tile-1's PW
  }
}

extern "C" void kernel_launch(void* const* d_in, const int* in_sizes, int n_in,
                              void* d_out, int out_size, void* d_ws, size_t ws_size,
                              hipStream_t stream) {
  (void)in_sizes; (void)n_in; (void)d_ws; (void)ws_size; (void)out_size;
  const float* q  = (const float*)d_in[0];
  const float* k  = (const float*)d_in[1];
  const float* v  = (const float*)d_in[2];
  const float* wq = (const float*)d_in[3];
  const float* bq = (const float*)d_in[4];
  const float* wk = (const float*)d_in[5];
  const float* bk = (const float*)d_in[6];
  const float* wv = (const float*)d_in[7];
  const float* bv = (const float*)d_in[8];
  float* out = (float*)d_out;
  fused_mha<<<dim3(2048), dim3(512), 0, stream>>>(q, k, v, wq, bq, wk, bk, wv, bv, out);
}

// Round 7
// 115.050 us; speedup vs baseline: 1.5966x; 1.5966x over previous
//
#include <hip/hip_runtime.h>
#include <hip/hip_bf16.h>

// Fused: O = Q (Wq^T (Kp^T Vp)) + bq·(Kp^T Vp) + residual q   (no softmax ->
// double associativity: fold Wq AND bq into the tiny 64x64 matrix U and the
// 64-vector r; the Qp materialization phase is deleted entirely).
// Round 7: R2's EXACT dispatch/residency shape (4096 one-shot blocks, natural
// order, ~78KB LDS, 2 blocks/CU) -- proven traffic floor (WRITE=output exactly,
// FETCH=197MB). Only the serial per-block path is shortened.

typedef __bf16 bf16x8 __attribute__((ext_vector_type(8)));
typedef float  f32x4  __attribute__((ext_vector_type(4)));

#define LDP 68    // row stride (bf16 elems): 136B rows, 8B-aligned
#define LDX 132   // channel-major row stride: 264B rows, 8B-aligned

// LDS regions (ushort offsets)
#define OF_A 0        // sK[128][68]  -> later sTt[64][68]
#define OF_B 8704     // sV[128][68]  -> later sQ[128][68]
#define OF_C 17408    // sKPt[64][132]-> later sUt[64][68]
#define OF_D 25856    // sVPt[64][132]
#define OF_W 34304    // sWqT[64][68]  (WqT[c][d] = Wq[d][c])
#define OF_SB 38656   // float sB[128]: [0:64)=bk [64:128)=bv
#define OF_SR 38912   // float sR[64]: r[c'] = sum_d bq[d] T[d][c']
#define LDS_USHORTS (38912 + 128)

// XOR swizzle (16B granule, key = row bits 2..4) for staged-input buffers only
#define SWZ(row, col) ((col) ^ ((((row) >> 2) & 7) << 3))

__device__ __forceinline__ unsigned short f2bf(float x) {
  __hip_bfloat16 h = __float2bfloat16(x);           // RNE
  return __builtin_bit_cast(unsigned short, h);
}
__device__ __forceinline__ float bf2f(unsigned short u) {
  unsigned int t = ((unsigned int)u) << 16;
  return __builtin_bit_cast(float, t);
}
__device__ __forceinline__ unsigned int pack2(float a, float b) {
  return (unsigned int)f2bf(a) | ((unsigned int)f2bf(b) << 16);
}
__device__ __forceinline__ bf16x8 cvt8(float4 a, float4 b) {
  union { unsigned int u[4]; bf16x8 v; } r;
  r.u[0] = pack2(a.x, a.y); r.u[1] = pack2(a.z, a.w);
  r.u[2] = pack2(b.x, b.y); r.u[3] = pack2(b.z, b.w);
  return r.v;
}
// load 8 contiguous bf16 (8B-aligned) as an MFMA fragment
__device__ __forceinline__ bf16x8 ld8(const unsigned short* p) {
  uint2 lo = *reinterpret_cast<const uint2*>(p);
  uint2 hi = *reinterpret_cast<const uint2*>(p + 4);
  uint4 t;
  t.x = lo.x; t.y = lo.y; t.z = hi.x; t.w = hi.y;
  return __builtin_bit_cast(bf16x8, t);
}

__global__ __launch_bounds__(512, 4)
void fused_mha(const float* __restrict__ q, const float* __restrict__ k,
               const float* __restrict__ v,
               const float* __restrict__ wq, const float* __restrict__ bq,
               const float* __restrict__ wk, const float* __restrict__ bk,
               const float* __restrict__ wv, const float* __restrict__ bv,
               float* __restrict__ out)
{
  __shared__ __align__(16) unsigned short lds[LDS_USHORTS];
  unsigned short* sK   = lds + OF_A;   // [128][LDP] pixel-major bf16 (SWZ)
  unsigned short* sV   = lds + OF_B;   // (SWZ)
  unsigned short* sKPt = lds + OF_C;   // [64][LDX] channel-major (plain)
  unsigned short* sVPt = lds + OF_D;   // (plain)
  unsigned short* sWqT = lds + OF_W;   // [c][d] = Wq[d][c] (plain)
  unsigned short* sTt  = lds + OF_A;   // [64][LDP] Tt[c'][d]=T[d][c'] (aliases dead sK)
  unsigned short* sQ   = lds + OF_B;   // [128][LDP] (aliases dead sV, SWZ)
  unsigned short* sUt  = lds + OF_C;   // [64][LDP] Ut[c'][c]=U[c][c'] (aliases dead sKPt)
  float* sB = (float*)(lds + OF_SB);
  float* sR = (float*)(lds + OF_SR);

  const int tid  = threadIdx.x;
  const int lane = tid & 63;
  const int ww   = tid >> 6;     // wave 0..7
  const int l15  = lane & 15;
  const int g    = lane >> 4;    // 0..3

  const size_t CS = 128*128;
  const int bh = blockIdx.x;
  const size_t base = (size_t)(bh >> 7)*(64*CS) + (size_t)(bh & 127)*128;

  // staging thread mapping: 4 consecutive w rows, 2 channels, 2 units
  const int sw0   = 4*(tid & 31);
  const int scA   = 2*((tid >> 5) & 15);
  const int swsel = ((tid & 31) & 7) << 3;   // ((row>>2)&7)<<3 for rows sw0..+3

  // ---------------- prologue ----------------
  // input loads (HBM latency starts now)
  float4 qreg[4], kreg[4], vreg[4];
  #pragma unroll
  for (int u = 0; u < 2; ++u) {
    int c = scA + 32*u;
    const float* pq = q + base + (size_t)c*CS + sw0;
    const float* pk = k + base + (size_t)c*CS + sw0;
    const float* pv = v + base + (size_t)c*CS + sw0;
    qreg[2*u+0] = *(const float4*)pq;  qreg[2*u+1] = *(const float4*)(pq + CS);
    kreg[2*u+0] = *(const float4*)pk;  kreg[2*u+1] = *(const float4*)(pk + CS);
    vreg[2*u+0] = *(const float4*)pv;  vreg[2*u+1] = *(const float4*)(pv + CS);
  }
  // Wk/Wv register fragments (wave's o-tile rt)
  const int rt = ww & 3;
  const int cb = (ww >> 2) * 4;
  bf16x8 wkf[2], wvf[2];
  #pragma unroll
  for (int ks = 0; ks < 2; ++ks) {
    const float* pk = wk + (16*rt + l15)*64 + 8*g + 32*ks;
    const float* pv = wv + (16*rt + l15)*64 + 8*g + 32*ks;
    wkf[ks] = cvt8(*(const float4*)pk, *(const float4*)(pk+4));
    wvf[ks] = cvt8(*(const float4*)pv, *(const float4*)(pv+4));
  }
  // bq fragments (only waves 0-3 consume them, for the r row-tile)
  bf16x8 bqf[2];
  if (ww < 4) {
    #pragma unroll
    for (int ks = 0; ks < 2; ++ks) {
      const float* pb = bq + 8*g + 32*ks;
      bqf[ks] = cvt8(*(const float4*)pb, *(const float4*)(pb+4));
    }
  }
  // stage Wq TRANSPOSED: sWqT[c][d] = Wq[d][c]
  {
    const int d0 = 2*(tid & 31);          // d pair
    const int c0 = 4*((tid >> 5) & 15);   // c quad
    float4 ra = *(const float4*)(wq + d0*64 + c0);
    float4 rb = *(const float4*)(wq + (d0+1)*64 + c0);
    const float* raf = (const float*)&ra;
    const float* rbf = (const float*)&rb;
    #pragma unroll
    for (int j = 0; j < 4; ++j)
      *(unsigned int*)&sWqT[(c0+j)*LDP + d0] = pack2(raf[j], rbf[j]);
  }
  if (tid < 64)        sB[tid] = bk[tid];
  else if (tid < 128)  sB[tid] = bv[tid-64];

  // PW: drain kreg/vreg -> sK/sV (swizzled)
  #pragma unroll
  for (int u = 0; u < 2; ++u) {
    int c = (scA + 32*u) ^ swsel;
    const float* ka = (const float*)&kreg[2*u];
    const float* kb = (const float*)&kreg[2*u+1];
    const float* va = (const float*)&vreg[2*u];
    const float* vb = (const float*)&vreg[2*u+1];
    #pragma unroll
    for (int j = 0; j < 4; ++j) {
      *(unsigned int*)&sK[(sw0+j)*LDP + c] = pack2(ka[j], kb[j]);
      *(unsigned int*)&sV[(sw0+j)*LDP + c] = pack2(va[j], vb[j]);
    }
  }
  __syncthreads();                                   // B1

  // ---------- P1: Kp^T[o][x], Vp^T[o][x] ----------
  {
    f32x4 z = {0.f,0.f,0.f,0.f};
    f32x4 acck[4] = {z,z,z,z}, accv[4] = {z,z,z,z};
    #pragma unroll
    for (int ks = 0; ks < 2; ++ks) {
      #pragma unroll
      for (int cc = 0; cc < 4; ++cc) {
        int row = 16*(cb+cc) + l15;
        int col = SWZ(row, 32*ks + 8*g);
        bf16x8 bk8 = ld8(&sK[row*LDP + col]);
        bf16x8 bv8 = ld8(&sV[row*LDP + col]);
        acck[cc] = __builtin_amdgcn_mfma_f32_16x16x32_bf16(wkf[ks], bk8, acck[cc], 0, 0, 0);
        accv[cc] = __builtin_amdgcn_mfma_f32_16x16x32_bf16(wvf[ks], bv8, accv[cc], 0, 0, 0);
      }
    }
    #pragma unroll
    for (int cc = 0; cc < 4; ++cc) {
      int x = 16*(cb+cc) + l15;
      #pragma unroll
      for (int r = 0; r < 4; ++r) {
        int o = 16*rt + 4*g + r;
        sKPt[o*LDX + x] = f2bf(acck[cc][r] + sB[o]);        // + bk
        sVPt[o*LDX + x] = f2bf(accv[cc][r] + sB[64 + o]);   // + bv
      }
    }
  }
  __syncthreads();                                   // B2

  // ---------- P2: Tt[c'][d] = sum_x Vp^T[c'][x] Kp^T[d][x]; drain q -> sQ ----
  {
    const int rt2 = ww >> 1;
    const int cb2 = (ww & 1) * 2;
    f32x4 z = {0.f,0.f,0.f,0.f};
    f32x4 acc[2] = {z,z};
    #pragma unroll
    for (int ks = 0; ks < 4; ++ks) {
      bf16x8 a = ld8(&sVPt[(16*rt2 + l15)*LDX + 32*ks + 8*g]);
      #pragma unroll
      for (int cc = 0; cc < 2; ++cc) {
        bf16x8 b = ld8(&sKPt[(16*(cb2+cc) + l15)*LDX + 32*ks + 8*g]);
        acc[cc] = __builtin_amdgcn_mfma_f32_16x16x32_bf16(a, b, acc[cc], 0, 0, 0);
      }
    }
    // drain q regs -> sQ (sV region dead after P1)
    #pragma unroll
    for (int u = 0; u < 2; ++u) {
      int c = (scA + 32*u) ^ swsel;
      const float* qa = (const float*)&qreg[2*u];
      const float* qb = (const float*)&qreg[2*u+1];
      #pragma unroll
      for (int j = 0; j < 4; ++j)
        *(unsigned int*)&sQ[(sw0+j)*LDP + c] = pack2(qa[j], qb[j]);
    }
    #pragma unroll
    for (int cc = 0; cc < 2; ++cc) {
      int d = 16*(cb2+cc) + l15;
      #pragma unroll
      for (int r = 0; r < 4; ++r)
        sTt[(16*rt2 + 4*g + r)*LDP + d] = f2bf(acc[cc][r]);
    }
  }
  __syncthreads();                                   // B3

  // ---------- P3': U[c][c'] = sum_d WqT[c][d] T[d][c']; r[c'] = sum_d bq[d] T[d][c'] ----
  // 16 U-tiles over 8 waves (2 each); r folded as a bq-masked row-tile on waves 0-3.
  {
    const int rtm = ww & 3;            // c row-tile
    const int cn0 = (ww >> 2) * 2;     // c' col-tile pair
    f32x4 z = {0.f,0.f,0.f,0.f};
    f32x4 u0 = z, u1 = z, rr = z;
    const bf16x8 zero8 = {};
    #pragma unroll
    for (int ks = 0; ks < 2; ++ks) {
      bf16x8 af = ld8(&sWqT[(16*rtm + l15)*LDP + 32*ks + 8*g]);
      bf16x8 b0 = ld8(&sTt[(16*(cn0+0) + l15)*LDP + 32*ks + 8*g]);
      bf16x8 b1 = ld8(&sTt[(16*(cn0+1) + l15)*LDP + 32*ks + 8*g]);
      u0 = __builtin_amdgcn_mfma_f32_16x16x32_bf16(af, b0, u0, 0, 0, 0);
      u1 = __builtin_amdgcn_mfma_f32_16x16x32_bf16(af, b1, u1, 0, 0, 0);
      if (ww < 4) {     // r row-tile: A row 0 = bq, rows 1-15 = 0
        bf16x8 ab = (l15 == 0) ? bqf[ks] : zero8;
        bf16x8 br = ld8(&sTt[(16*ww + l15)*LDP + 32*ks + 8*g]);
        rr = __builtin_amdgcn_mfma_f32_16x16x32_bf16(ab, br, rr, 0, 0, 0);
      }
    }
    // write Ut[c'][c]: row n = 16*cn + l15, cols m = 16*rtm + 4g + (0..3) (b64)
    uint2 wo;
    wo.x = pack2(u0[0], u0[1]); wo.y = pack2(u0[2], u0[3]);
    *(uint2*)&sUt[(16*(cn0+0) + l15)*LDP + 16*rtm + 4*g] = wo;
    wo.x = pack2(u1[0], u1[1]); wo.y = pack2(u1[2], u1[3]);
    *(uint2*)&sUt[(16*(cn0+1) + l15)*LDP + 16*rtm + 4*g] = wo;
    if (ww < 4 && g == 0) sR[16*ww + l15] = rr[0];   // D row m=0 only
  }
  __syncthreads();                                   // B4

  // ---------- P4: O[w][c'] = sum_c Q[w][c] U[c][c'] + r[c']; out = O + q ----
  {
    f32x4 z = {0.f,0.f,0.f,0.f};
    f32x4 acc[4] = {z,z,z,z};
    #pragma unroll
    for (int ks = 0; ks < 2; ++ks) {
      int arow = 16*ww + l15;
      bf16x8 a = ld8(&sQ[arow*LDP + SWZ(arow, 32*ks + 8*g)]);
      #pragma unroll
      for (int ct = 0; ct < 4; ++ct) {
        bf16x8 b = ld8(&sUt[(16*ct + l15)*LDP + 32*ks + 8*g]);
        acc[ct] = __builtin_amdgcn_mfma_f32_16x16x32_bf16(a, b, acc[ct], 0, 0, 0);
      }
    }
    #pragma unroll
    for (int ct = 0; ct < 4; ++ct) {
      int c  = 16*ct + l15;
      int w0 = 16*ww + 4*g;
      float rv = sR[c];
      float4 o4;
      o4.x = acc[ct][0] + rv + bf2f(sQ[(w0+0)*LDP + SWZ(w0+0, c)]);
      o4.y = acc[ct][1] + rv + bf2f(sQ[(w0+1)*LDP + SWZ(w0+1, c)]);
      o4.z = acc[ct][2] + rv + bf2f(sQ[(w0+2)*LDP + SWZ(w0+2, c)]);
      o4.w = acc[ct][3] + rv + bf2f(sQ[(w0+3)*LDP + SWZ(w0+3, c)]);
      *reinterpret_cast<float4*>(out + base + (size_t)c * CS + w0) = o4;
    }
  }
}

extern "C" void kernel_launch(void* const* d_in, const int* in_sizes, int n_in,
                              void* d_out, int out_size, void* d_ws, size_t ws_size,
                              hipStream_t stream) {
  (void)in_sizes; (void)n_in; (void)d_ws; (void)ws_size; (void)out_size;
  const float* q  = (const float*)d_in[0];
  const float* k  = (const float*)d_in[1];
  const float* v  = (const float*)d_in[2];
  const float* wq = (const float*)d_in[3];
  const float* bq = (const float*)d_in[4];
  const float* wk = (const float*)d_in[5];
  const float* bk = (const float*)d_in[6];
  const float* wv = (const float*)d_in[7];
  const float* bv = (const float*)d_in[8];
  float* out = (float*)d_out;
  fused_mha<<<dim3(32*128), dim3(512), 0, stream>>>(q, k, v, wq, bq, wk, bk, wv, bv, out);
}